// Round 1
// baseline (507.988 us; speedup 1.0000x reference)
//
#include <hip/hip_runtime.h>

// SimpleRNN: h_{t+1} = tanh(h_t @ H^T + x_t @ U + b); out = h_T @ A^T + c
// T=512 B=2048 IN=28 HID=198 OUT=10, fp32 in/out, fp16 recurrence (R8 math).
//
// R9 (from R8: dispatch 360us, 1688 cyc/step). Step decomposition: MFMA
// 504 avg / 620 worst-SIMD, LDS A-frag pipe ~830 (13 waves redundantly
// re-read the same fragments), stager HBM latency ~900 serialized behind
// the per-step barrier. Two changes:
//  1. Depth-2 software-pipelined x-stager: x[t+3] global-loaded into regs
//     during step t, cvt+ds_write at t+2 -> HBM latency off the
//     barrier-to-barrier critical path. Time loop unrolled x2 so the two
//     reg slots are statically named (no runtime-indexed reg arrays).
//  2. 8 waves (512 thr): waves 0-4 compute TWO 16-col N-tiles (cols
//     16w+m and 128+16w+m) off ONE shared A-frag read set (4 independent
//     MFMA chains = 2x per-wave ILP); waves 5-7 one tile. LDS reads
//     104 -> 64 ds_read_b128/step; per-SIMD MFMA balanced at <=32
//     (= ceil(13 tiles/4 SIMDs), which R8's SIMD0 already paid).
//     Wave 5 (light, SIMD1) doubles as stager on lanes 0-31.
// LDS layout, epilogue row mapping (C rows 8-15 dup 0-7), fp16 single-pass
// recurrence all unchanged from R8.

#define T_STEPS 512
#define BATCH   2048
#define IN_DIM  28
#define HID     198
#define OUT_DIM 10
#define BB      8      // batch rows per block
#define KT      8      // 7 H k-tiles of 32 (224 >= 198) + 1 U/x slot
#define NTHREADS 512   // 8 waves

typedef __attribute__((ext_vector_type(8))) _Float16 half8;
typedef __attribute__((ext_vector_type(4))) float   floatx4;

__device__ __forceinline__ floatx4 mfma16(half8 a, half8 b, floatx4 c) {
    return __builtin_amdgcn_mfma_f32_16x16x32_f16(a, b, c, 0, 0, 0);
}

// tanh(x) = 1 - 2/(exp(2x)+1); exp2-based, saturates via IEEE inf/0.
__device__ __forceinline__ float fast_tanh(float x) {
    float e = __builtin_amdgcn_exp2f(x * 2.885390081777926357f); // exp(2x)
    float r = __builtin_amdgcn_rcpf(e + 1.0f);
    return __builtin_fmaf(-2.0f, r, 1.0f);
}

__global__ void __launch_bounds__(NTHREADS, 1)
rnn_kernel(const float* __restrict__ x, const float* __restrict__ H,
           const float* __restrict__ U, const float* __restrict__ A,
           const float* __restrict__ bvec, const float* __restrict__ cvec,
           float* __restrict__ out)
{
    // A-frag ping-pong: [buf][kt][chunk*8 + r8][idx], fp16. Compute lane
    // (m,quad) reads 16B at [kt][quad*8 + (m&7)] - lanes m and m+8 hit the
    // same address (2-way broadcast, free).
    __shared__ __align__(16) _Float16 lds_A[2][KT][32][8];   // 8 KB
    __shared__ float lds_h[BB][204];                          // final h, fp32

    const int tid  = threadIdx.x;
    const int lane = tid & 63;
    const int wv   = tid >> 6;          // wave id 0..7
    const int m    = lane & 15;
    const int quad = lane >> 4;         // 0..3
    const int r8   = m & 7;
    const int b0   = blockIdx.x * BB;
    const bool heavy = (wv < 5);        // waves 0-4 carry a 2nd N-tile

    // zero-init both buffers (h0 = 0; phantom K rows stay 0 forever)
    {
        _Float16* p0 = &lds_A[0][0][0][0];
        for (int i = tid; i < 2*KT*32*8; i += NTHREADS) p0[i] = (_Float16)0.0f;
    }

    const floatx4 zero4 = {0.0f, 0.0f, 0.0f, 0.0f};

    // ---- stationary fp16 B fragments: tile A (all waves), tile B (heavy) ----
    const int jcolA = wv*16 + m;        // < 128, always real
    const int jcolB = jcolA + 128;      // heavy waves; may be phantom (>=198)
    const bool bReal = heavy && (jcolB < HID);
    const float biasA = bvec[jcolA];
    const float biasB = bReal ? bvec[jcolB] : 0.0f;

    half8 BfA[KT], BfB[KT];
    #pragma unroll
    for (int kt = 0; kt < 7; ++kt) {
        half8 fa, fb;
        #pragma unroll
        for (int idx = 0; idx < 8; ++idx) {
            const int k = kt*32 + quad*8 + idx;               // B[k][j] = H[j][k]
            fa[idx] = (_Float16)((k < HID) ? H[jcolA*HID + k] : 0.0f);
            fb[idx] = (_Float16)((bReal && k < HID) ? H[jcolB*HID + k] : 0.0f);
        }
        BfA[kt] = fa; BfB[kt] = fb;
    }
    {   // slot 7: U
        half8 fa, fb;
        #pragma unroll
        for (int idx = 0; idx < 8; ++idx) {
            const int i = quad*8 + idx;
            fa[idx] = (_Float16)((i < IN_DIM) ? U[i*HID + jcolA] : 0.0f);
            fb[idx] = (_Float16)((bReal && i < IN_DIM) ? U[i*HID + jcolB] : 0.0f);
        }
        BfA[7] = fa; BfB[7] = fb;
    }

    const int eA_ktd = jcolA >> 5, eA_c8 = ((jcolA & 31) >> 3)*8, eA_idx = jcolA & 7;
    const int eB_ktd = jcolB >> 5, eB_c8 = ((jcolB & 31) >> 3)*8, eB_idx = jcolB & 7;
    const int regbase = (quad >> 1) * 2;            // epilogue: 0 or 2

    // ---- x stager state (wave 5, lanes 0-31): depth-2 register pipeline ----
    const int srow = lane & 31, sq = srow >> 3, sr8 = srow & 7;
    const float* xrow_s = x + (size_t)(b0 + sr8) * IN_DIM + sq*8;
    const size_t tstride = (size_t)BATCH * IN_DIM;
    floatx4 sA0 = zero4, sA1 = zero4, sB0 = zero4, sB1 = zero4;

    auto issueLd = [&](int tn, floatx4& f0, floatx4& f1) {
        const float* p = xrow_s + (size_t)tn * tstride;
        f0 = *(const floatx4*)p;
        f1 = (sq < 3) ? *(const floatx4*)(p + 4) : zero4;     // IN=28 tail zeroed
    };
    auto commitX = [&](floatx4 f0, floatx4 f1, int buf) {
        half8 ax;
        ax[0] = (_Float16)f0[0]; ax[1] = (_Float16)f0[1];
        ax[2] = (_Float16)f0[2]; ax[3] = (_Float16)f0[3];
        ax[4] = (_Float16)f1[0]; ax[5] = (_Float16)f1[1];
        ax[6] = (_Float16)f1[2]; ax[7] = (_Float16)f1[3];
        *(half8*)&lds_A[buf][7][srow][0] = ax;
    };

    __syncthreads();   // zero-fill visible before slot-7 prologue write

    if (wv == 5 && lane < 32) {
        floatx4 t0, t1;
        issueLd(0, t0, t1);           // x[0]
        issueLd(1, sA0, sA1);         // x[1] -> slot A
        issueLd(2, sB0, sB1);         // x[2] -> slot B
        commitX(t0, t1, 0);           // x[0] into buf 0 (read at step 0)
    }

    auto computeStep = [&](int rb, int wb, bool last) {
        floatx4 aA1 = {biasA, biasA, biasA, biasA};
        floatx4 aA2 = zero4;
        floatx4 aB1 = {biasB, biasB, biasB, biasB};
        floatx4 aB2 = zero4;
        #pragma unroll
        for (int kt = 0; kt < KT; ++kt) {
            const half8 av = *(const half8*)&lds_A[rb][kt][quad*8 + r8][0];
            if (kt & 1) {
                aA2 = mfma16(av, BfA[kt], aA2);
                if (heavy) aB2 = mfma16(av, BfB[kt], aB2);
            } else {
                aA1 = mfma16(av, BfA[kt], aA1);
                if (heavy) aB1 = mfma16(av, BfB[kt], aB1);
            }
        }
        // epilogue: rows split over quads; C rows 8-15 dup rows 0-7, so
        // quad0:{r0,r1}->rows{0,1} quad1->{4,5} quad2:{r2,r3}->rows{2,3}
        // quad3->{6,7}. 2 tanh (4 if heavy+real) + fp16 LDS writes per lane.
        #pragma unroll
        for (int e = 0; e < 2; ++e) {
            const int reg = regbase + e;
            const int row = (quad & 1)*4 + reg;
            const float vA = fast_tanh(aA1[reg] + aA2[reg]);
            lds_A[wb][eA_ktd][eA_c8 + row][eA_idx] = (_Float16)vA;
            if (last) lds_h[row][jcolA] = vA;
            if (bReal) {
                const float vB = fast_tanh(aB1[reg] + aB2[reg]);
                lds_A[wb][eB_ktd][eB_c8 + row][eB_idx] = (_Float16)vB;
                if (last) lds_h[row][jcolB] = vB;
            }
        }
    };

    // ================= time loop, 2 steps/iter (static reg slots) =========
    // even step t:  commit slot A (x[t+1]) -> buf1, refill A with x[t+3]
    // odd step t+1: commit slot B (x[t+2]) -> buf0, refill B with x[t+4]
    // load-to-commit window = 2 full steps >> ~900cy HBM latency.
    #pragma unroll 1
    for (int t = 0; t < T_STEPS; t += 2) {
        __syncthreads();
        if (wv == 5 && lane < 32) {
            commitX(sA0, sA1, 1);
            const int tn = (t+3 < T_STEPS) ? (t+3) : (T_STEPS-1);
            issueLd(tn, sA0, sA1);
        }
        computeStep(0, 1, false);

        __syncthreads();
        if (wv == 5 && lane < 32) {
            commitX(sB0, sB1, 0);
            const int tn = (t+4 < T_STEPS) ? (t+4) : (T_STEPS-1);
            issueLd(tn, sB0, sB1);
        }
        computeStep(1, 0, (t + 2) == T_STEPS);
    }

    __syncthreads();

    // ---- output: out[b][o] = sum_k h[b][k]*A[o][k] + c[o] (tiny, scalar) ----
    if (tid < BB * OUT_DIM) {
        const int r = tid / OUT_DIM;
        const int o = tid % OUT_DIM;
        float s = cvec[o];
        for (int k = 0; k < HID; ++k) s += lds_h[r][k] * A[o*HID + k];
        out[(size_t)(b0 + r) * OUT_DIM + o] = s;
    }
}

extern "C" void kernel_launch(void* const* d_in, const int* in_sizes, int n_in,
                              void* d_out, int out_size, void* d_ws, size_t ws_size,
                              hipStream_t stream) {
    const float* x  = (const float*)d_in[0];
    const float* H  = (const float*)d_in[1];
    const float* U  = (const float*)d_in[2];
    const float* A  = (const float*)d_in[3];
    const float* b  = (const float*)d_in[4];
    const float* c  = (const float*)d_in[5];
    float* out = (float*)d_out;

    rnn_kernel<<<dim3(BATCH / BB), dim3(NTHREADS), 0, stream>>>(x, H, U, A, b, c, out);
}

// Round 3
// 405.594 us; speedup vs baseline: 1.2525x; 1.2525x over previous
//
#include <hip/hip_runtime.h>

// SimpleRNN: h_{t+1} = tanh(h_t @ H^T + x_t @ U + b); out = h_T @ A^T + c
// T=512 B=2048 IN=28 HID=198 OUT=10, fp32 in/out, fp16 recurrence (R8 math).
//
// R11 = R10 with the DPP-divergence bug fixed.
// R10 (diagonal-block MFMA) FAILED correctness (absmax 1.76): the partial
// combine put ror8() (mov_dpp, a convergent op) inside the arms of a
// lane-divergent ternary. Convergent calls can't be hoisted out of branch
// arms, so EXEC was masked to half the lanes while the DPP ran; the source
// lane (l^8) was inactive -> DPP read 0 -> every lane lost its partner
// partial (and half lost the bias). Fix: pre-select (cndmask) the value
// the PARTNER needs, then ONE full-EXEC straight-line row_ror:8 per group,
// then select own reg and add. No convergent op under divergent control.
//
// Structure (R10, unchanged): diagonal-block MFMA.
//   A row 4Q+{0,1,2,3} = {b=2Q k-lo, b=2Q k-hi, b=2Q+1 k-lo, b=2Q+1 k-hi}
//   B cols 0-7 = 8 output cols @ k-lo, cols 8-15 = same cols @ k-hi
// One MFMA = 8 cols x K=64 (k-half partials on the C diagonal blocks).
// Per wave: 4 A-reads of all-unique 1024B (vs R8's 8 half-duplicated) and
// 8 MFMAs (wave 12 skips its all-phantom 2nd group -> 100 total, worst
// SIMD 28). 16 waves (R9 lesson: fewer is latency-dead). K layout:
// k 0..197 = H, k 224..251 = x (tau=3 k-hi slots), gaps zero forever.
// Stager: wave 15, depth-2 register pipeline: load x[t+3] during step t,
// commit at t+2 (HBM latency off the barrier-to-barrier critical path).

#define T_STEPS 512
#define BATCH   2048
#define IN_DIM  28
#define HID     198
#define OUT_DIM 10
#define BB      8      // batch rows per block
#define NTAU    4      // K-tiles of 64: 4*64=256 >= 198+28(+pad)
#define NTHREADS 1024  // 16 waves

typedef __attribute__((ext_vector_type(8))) _Float16 half8;
typedef __attribute__((ext_vector_type(4))) float   floatx4;

__device__ __forceinline__ floatx4 mfma16(half8 a, half8 b, floatx4 c) {
    return __builtin_amdgcn_mfma_f32_16x16x32_f16(a, b, c, 0, 0, 0);
}

// tanh(x) = 1 - 2/(exp(2x)+1); exp2-based, saturates via IEEE inf/0.
__device__ __forceinline__ float fast_tanh(float x) {
    float e = __builtin_amdgcn_exp2f(x * 2.885390081777926357f); // exp(2x)
    float r = __builtin_amdgcn_rcpf(e + 1.0f);
    return __builtin_fmaf(-2.0f, r, 1.0f);
}

// lane <- lane^8 within each 16-lane DPP row (row_ror:8; 8 is self-inverse
// mod 16). VALU pipe. MUST be called in full-EXEC straight-line code.
__device__ __forceinline__ float ror8(float v) {
    return __builtin_bit_cast(float,
        __builtin_amdgcn_mov_dpp(__builtin_bit_cast(int, v),
                                 0x128 /*row_ror:8*/, 0xf, 0xf, true));
}

__global__ void __launch_bounds__(NTHREADS, 4)
rnn_kernel(const float* __restrict__ x, const float* __restrict__ H,
           const float* __restrict__ U, const float* __restrict__ A,
           const float* __restrict__ bvec, const float* __restrict__ cvec,
           float* __restrict__ out)
{
    // A-frag ping-pong: [buf][tau][slot][idx] fp16, slot = khalf*32+kq*8+b.
    // Lane (n16,q) reads b128 at slot (n16&1)*32 + q*8 + bm(n16): 64 distinct
    // slots = 1024B unique per read, linear-b128 bank pattern.
    __shared__ __align__(16) _Float16 lds_A[2][NTAU][64][8];   // 8 KB
    __shared__ float lds_h[BB][204];                            // final h, fp32

    const int tid  = threadIdx.x;
    const int lane = tid & 63;
    const int wv   = tid >> 6;          // wave id 0..15
    const int n16  = lane & 15;         // MFMA row(A)/col(B,C) index
    const int q    = lane >> 4;         // 0..3 (k-octet within 32-subtile)
    const int b0   = blockIdx.x * BB;

    // zero-init both buffers (h0 = 0; phantom K rows stay 0 forever)
    {
        _Float16* p0 = &lds_A[0][0][0][0];
        for (int i = tid; i < 2*NTAU*64*8; i += NTHREADS) p0[i] = (_Float16)0.0f;
    }

    const floatx4 zero4 = {0.0f, 0.0f, 0.0f, 0.0f};
    const bool is_cw = (wv < 13);       // compute waves

    // ---- A-read slot: row n16 carries (batch bm, k-half khm) ----
    const int bm  = 2*(n16 >> 2) + ((n16 >> 1) & 1);
    const int khm = n16 & 1;
    const int aslot = khm*32 + q*8 + bm;

    // ---- col groups: g0 = cols wv*16..+7, g1 = wv*16+8..+15 ----
    const int jbase0 = wv*16;
    const int jbase1 = wv*16 + 8;
    const bool g1_on = is_cw && (jbase1 < HID);     // wave 12: g1 all-phantom
    const int jl = n16 & 7;
    const int j0 = jbase0 + jl;         // this lane's output col, group 0
    const int j1 = jbase1 + jl;         // group 1
    // epilogue ownership: lane (n16,q) finishes batch row 2q + (n16>>3)
    const int b_lane = 2*q + (n16 >> 3);

    // ---- stationary fp16 B fragments (H + U), diagonal k-half layout ----
    // B-op lane (n16,q) elem i: col n16; j = jbase + (n16&7);
    // k = tau*64 + (n16>>3)*32 + q*8 + i. k<198 -> H[j][k]; k in [224,252)
    // -> U[k-224][j]; else 0.
    half8 Bf0[NTAU], Bf1[NTAU];
    float bias0 = 0.0f, bias1 = 0.0f;
    if (is_cw) {
        bias0 = (n16 < 8 && j0 < HID) ? bvec[j0] : 0.0f;   // bias on lo-cols only
        bias1 = (n16 < 8 && g1_on)    ? bvec[j1] : 0.0f;
        #pragma unroll
        for (int tau = 0; tau < NTAU; ++tau) {
            half8 f0, f1;
            #pragma unroll
            for (int i = 0; i < 8; ++i) {
                const int k = tau*64 + (n16 >> 3)*32 + q*8 + i;
                float v0 = 0.0f, v1 = 0.0f;
                if (j0 < HID) {
                    if (k < HID)                          v0 = H[j0*HID + k];
                    else if (k >= 224 && k < 224+IN_DIM)  v0 = U[(k-224)*HID + j0];
                }
                if (g1_on) {
                    if (k < HID)                          v1 = H[j1*HID + k];
                    else if (k >= 224 && k < 224+IN_DIM)  v1 = U[(k-224)*HID + j1];
                }
                f0[i] = (_Float16)v0;
                f1[i] = (_Float16)v1;
            }
            Bf0[tau] = f0; Bf1[tau] = f1;
        }
    }

    // epilogue write addresses: h(b_lane, j) -> tau=j>>6,
    // slot = ((j>>5)&1)*32 + ((j>>3)&3)*8 + b_lane, idx = j&7
    const int e0_tau = j0 >> 6;
    const int e0_slot = ((j0 >> 5) & 1)*32 + ((j0 >> 3) & 3)*8 + b_lane;
    const int e0_idx = j0 & 7;
    const int e1_tau = j1 >> 6;
    const int e1_slot = ((j1 >> 5) & 1)*32 + ((j1 >> 3) & 3)*8 + b_lane;
    const int e1_idx = j1 & 7;

    // ---- x stager (wave 15, lanes 0-31): depth-2 register pipeline ----
    // x[xi] lives at k = 224+xi -> tau 3, slots 32..63: slot = 32 + srow.
    const int srow = lane & 31, sq = srow >> 3, sr8 = srow & 7;
    const float* xrow_s = x + (size_t)(b0 + sr8) * IN_DIM + sq*8;
    const size_t tstride = (size_t)BATCH * IN_DIM;
    floatx4 sA0 = zero4, sA1 = zero4, sB0 = zero4, sB1 = zero4;

    auto issueLd = [&](int tn, floatx4& f0, floatx4& f1) {
        const float* p = xrow_s + (size_t)tn * tstride;
        f0 = *(const floatx4*)p;
        f1 = (sq < 3) ? *(const floatx4*)(p + 4) : zero4;   // IN=28 tail zeroed
    };
    auto commitX = [&](floatx4 f0, floatx4 f1, int buf) {
        half8 ax;
        ax[0] = (_Float16)f0[0]; ax[1] = (_Float16)f0[1];
        ax[2] = (_Float16)f0[2]; ax[3] = (_Float16)f0[3];
        ax[4] = (_Float16)f1[0]; ax[5] = (_Float16)f1[1];
        ax[6] = (_Float16)f1[2]; ax[7] = (_Float16)f1[3];
        *(half8*)&lds_A[buf][3][32 + srow][0] = ax;
    };

    __syncthreads();   // zero-fill visible before prologue writes

    if (wv == 15 && lane < 32) {
        floatx4 t0, t1;
        issueLd(0, t0, t1);           // x[0]
        issueLd(1, sA0, sA1);         // x[1] -> slot A
        issueLd(2, sB0, sB1);         // x[2] -> slot B
        commitX(t0, t1, 0);           // x[0] into buf 0 (read at step 0)
    }

    auto computeStep = [&](int rb, int wb, bool last) {
        if (!is_cw) return;
        floatx4 a0 = {bias0, bias0, bias0, bias0};
        floatx4 a1 = {bias1, bias1, bias1, bias1};
        #pragma unroll
        for (int tau = 0; tau < NTAU; ++tau) {
            const half8 av = *(const half8*)&lds_A[rb][tau][aslot][0];
            a0 = mfma16(av, Bf0[tau], a0);
            if (g1_on) a1 = mfma16(av, Bf1[tau], a1);
        }
        // ---- combine diagonal partials, DPP in full-EXEC straight line ----
        // Lane holds D[4q+r][n16]: r0=(b=2q,lo) r1=(b=2q,hi) r2=(b=2q+1,lo)
        // r3=(b=2q+1,hi). Lo-lane (n16<8) finishes b=2q, needs partner's r1;
        // hi-lane finishes b=2q+1, needs partner's r2. Pre-select what the
        // PARTNER needs (cndmask on plain floats), ONE row_ror:8 per group,
        // then own-reg select + add. No convergent op under divergent flow.
        const float send0 = (n16 < 8) ? a0[2] : a0[1];
        const float send1 = (n16 < 8) ? a1[2] : a1[1];
        const float recv0 = ror8(send0);
        const float recv1 = ror8(send1);
        const float s0 = ((n16 < 8) ? a0[0] : a0[3]) + recv0;
        const float s1 = ((n16 < 8) ? a1[0] : a1[3]) + recv1;
        if (j0 < HID) {
            const float v = fast_tanh(s0);
            lds_A[wb][e0_tau][e0_slot][e0_idx] = (_Float16)v;
            if (last) lds_h[b_lane][j0] = v;
        }
        if (g1_on) {
            const float v = fast_tanh(s1);
            lds_A[wb][e1_tau][e1_slot][e1_idx] = (_Float16)v;
            if (last) lds_h[b_lane][j1] = v;
        }
    };

    // ================= time loop, 2 steps/iter (static reg slots) =========
    // even step t:  commit slot A (x[t+1]) -> buf1, refill A with x[t+3]
    // odd step t+1: commit slot B (x[t+2]) -> buf0, refill B with x[t+4]
    #pragma unroll 1
    for (int t = 0; t < T_STEPS; t += 2) {
        __syncthreads();
        if (wv == 15 && lane < 32) {
            commitX(sA0, sA1, 1);
            const int tn = (t+3 < T_STEPS) ? (t+3) : (T_STEPS-1);
            issueLd(tn, sA0, sA1);
        }
        computeStep(0, 1, false);

        __syncthreads();
        if (wv == 15 && lane < 32) {
            commitX(sB0, sB1, 0);
            const int tn = (t+4 < T_STEPS) ? (t+4) : (T_STEPS-1);
            issueLd(tn, sB0, sB1);
        }
        computeStep(1, 0, (t + 2) == T_STEPS);
    }

    __syncthreads();

    // ---- output: out[b][o] = sum_k h[b][k]*A[o][k] + c[o] (tiny, scalar) ----
    if (tid < BB * OUT_DIM) {
        const int r = tid / OUT_DIM;
        const int o = tid % OUT_DIM;
        float s = cvec[o];
        for (int k = 0; k < HID; ++k) s += lds_h[r][k] * A[o*HID + k];
        out[(size_t)(b0 + r) * OUT_DIM + o] = s;
    }
}

extern "C" void kernel_launch(void* const* d_in, const int* in_sizes, int n_in,
                              void* d_out, int out_size, void* d_ws, size_t ws_size,
                              hipStream_t stream) {
    const float* x  = (const float*)d_in[0];
    const float* H  = (const float*)d_in[1];
    const float* U  = (const float*)d_in[2];
    const float* A  = (const float*)d_in[3];
    const float* b  = (const float*)d_in[4];
    const float* c  = (const float*)d_in[5];
    float* out = (float*)d_out;

    rnn_kernel<<<dim3(BATCH / BB), dim3(NTHREADS), 0, stream>>>(x, H, U, A, b, c, out);
}

// Round 4
// 404.992 us; speedup vs baseline: 1.2543x; 1.0015x over previous
//
#include <hip/hip_runtime.h>

// SimpleRNN: h_{t+1} = tanh(h_t @ H^T + x_t @ U + b); out = h_T @ A^T + c
// T=512 B=2048 IN=28 HID=198 OUT=10, fp32 in/out, fp16 recurrence.
//
// R12 = R11 with the A-slot map relabeled for conflict-free ds_read_b128.
// R11 (303us, step 1424cyc) measured SQ_LDS_BANK_CONFLICT 27.3M (208
// cyc/CU-step): slot = khm*32 + q*8 + bm puts slots s and s+32 on the same
// banks at different rows within each 16-lane phase (byte distance 512 =
// bank-period). Fix: lane l reads slot l (stride-1 linear b128 = free);
// writers use the inverse map slot(b,khalf,kq) = kq*16+(b>>1)*4+(b&1)*2+khalf.
// Pure relabeling - A-row<->(b,khalf) assignment, B frags, combine, stager
// all unchanged from R11 (which passed, absmax 0.0078).
//
// Structure (R10/R11): diagonal-block MFMA.
//   A row m = 4q+r carries (b = 2q+(r>>1), khalf = r&1); B cols 0-7 = 8
//   output cols @ k-lo, cols 8-15 = same cols @ k-hi. One 16x16x32 MFMA
//   = 8 cols x K=64 (k-half partials on the C diagonal blocks).
// Per wave: 4 A-reads of all-unique 1024B, 8 MFMAs (wave 12 skips its
// all-phantom 2nd group -> 100 total, worst SIMD 28). 16 waves (R9
// lesson: 8 waves = 2/SIMD is latency-dead). K layout: k 0..197 = H,
// k 224..251 = x (tau=3), gaps zero forever.
// Stager: wave 15, depth-2 register pipeline: load x[t+3] during step t,
// commit at t+2 (HBM latency off the barrier-to-barrier critical path).
// Combine: DPP row_ror:8 in full-EXEC straight line only (R10 lesson:
// convergent ops must not sit in divergent ternary arms).

#define T_STEPS 512
#define BATCH   2048
#define IN_DIM  28
#define HID     198
#define OUT_DIM 10
#define BB      8      // batch rows per block
#define NTAU    4      // K-tiles of 64: 4*64=256 >= 198+28(+pad)
#define NTHREADS 1024  // 16 waves

typedef __attribute__((ext_vector_type(8))) _Float16 half8;
typedef __attribute__((ext_vector_type(4))) float   floatx4;

__device__ __forceinline__ floatx4 mfma16(half8 a, half8 b, floatx4 c) {
    return __builtin_amdgcn_mfma_f32_16x16x32_f16(a, b, c, 0, 0, 0);
}

// tanh(x) = 1 - 2/(exp(2x)+1); exp2-based, saturates via IEEE inf/0.
__device__ __forceinline__ float fast_tanh(float x) {
    float e = __builtin_amdgcn_exp2f(x * 2.885390081777926357f); // exp(2x)
    float r = __builtin_amdgcn_rcpf(e + 1.0f);
    return __builtin_fmaf(-2.0f, r, 1.0f);
}

// lane <- lane^8 within each 16-lane DPP row (row_ror:8; 8 is self-inverse
// mod 16). VALU pipe. MUST be called in full-EXEC straight-line code.
__device__ __forceinline__ float ror8(float v) {
    return __builtin_bit_cast(float,
        __builtin_amdgcn_mov_dpp(__builtin_bit_cast(int, v),
                                 0x128 /*row_ror:8*/, 0xf, 0xf, true));
}

__global__ void __launch_bounds__(NTHREADS, 4)
rnn_kernel(const float* __restrict__ x, const float* __restrict__ H,
           const float* __restrict__ U, const float* __restrict__ A,
           const float* __restrict__ bvec, const float* __restrict__ cvec,
           float* __restrict__ out)
{
    // A-frag ping-pong: [buf][tau][slot][idx] fp16.
    // slot(b, khalf, kq) = kq*16 + (b>>1)*4 + (b&1)*2 + khalf  <- inverse of
    // lane mapping, so compute lane l reads b128 at slot l (linear, 0-conflict).
    __shared__ __align__(16) _Float16 lds_A[2][NTAU][64][8];   // 8 KB
    __shared__ float lds_h[BB][204];                            // final h, fp32

    const int tid  = threadIdx.x;
    const int lane = tid & 63;
    const int wv   = tid >> 6;          // wave id 0..15
    const int n16  = lane & 15;         // MFMA row(A)/col(B,C) index
    const int q    = lane >> 4;         // 0..3 (k-octet within 32-subtile)
    const int b0   = blockIdx.x * BB;

    // zero-init both buffers (h0 = 0; phantom K rows stay 0 forever)
    {
        _Float16* p0 = &lds_A[0][0][0][0];
        for (int i = tid; i < 2*NTAU*64*8; i += NTHREADS) p0[i] = (_Float16)0.0f;
    }

    const floatx4 zero4 = {0.0f, 0.0f, 0.0f, 0.0f};
    const bool is_cw = (wv < 13);       // compute waves

    // ---- A-read: lane l reads slot l (linear).  Row m=4q+r of the MFMA
    // carries (b = 2q+(r>>1), khalf = r&1); this lane's slot content is
    // (b = 2*(n16>>2)+((n16>>1)&1), khalf = n16&1, k-octet q). ----
    const int aslot = lane;

    // ---- col groups: g0 = cols wv*16..+7, g1 = wv*16+8..+15 ----
    const int jbase0 = wv*16;
    const int jbase1 = wv*16 + 8;
    const bool g1_on = is_cw && (jbase1 < HID);     // wave 12: g1 all-phantom
    const int jl = n16 & 7;
    const int j0 = jbase0 + jl;         // this lane's output col, group 0
    const int j1 = jbase1 + jl;         // group 1
    // epilogue ownership: lane (n16,q) finishes batch row 2q + (n16>>3)
    const int b_lane = 2*q + (n16 >> 3);

    // ---- stationary fp16 B fragments (H + U), diagonal k-half layout ----
    // B-op lane (n16,q) elem i: col n16; j = jbase + (n16&7);
    // k = tau*64 + (n16>>3)*32 + q*8 + i. k<198 -> H[j][k]; k in [224,252)
    // -> U[k-224][j]; else 0.
    half8 Bf0[NTAU], Bf1[NTAU];
    float bias0 = 0.0f, bias1 = 0.0f;
    if (is_cw) {
        bias0 = (n16 < 8 && j0 < HID) ? bvec[j0] : 0.0f;   // bias on lo-cols only
        bias1 = (n16 < 8 && g1_on)    ? bvec[j1] : 0.0f;
        #pragma unroll
        for (int tau = 0; tau < NTAU; ++tau) {
            half8 f0, f1;
            #pragma unroll
            for (int i = 0; i < 8; ++i) {
                const int k = tau*64 + (n16 >> 3)*32 + q*8 + i;
                float v0 = 0.0f, v1 = 0.0f;
                if (j0 < HID) {
                    if (k < HID)                          v0 = H[j0*HID + k];
                    else if (k >= 224 && k < 224+IN_DIM)  v0 = U[(k-224)*HID + j0];
                }
                if (g1_on) {
                    if (k < HID)                          v1 = H[j1*HID + k];
                    else if (k >= 224 && k < 224+IN_DIM)  v1 = U[(k-224)*HID + j1];
                }
                f0[i] = (_Float16)v0;
                f1[i] = (_Float16)v1;
            }
            Bf0[tau] = f0; Bf1[tau] = f1;
        }
    }

    // epilogue write addresses for h(b_lane, j):
    // tau = j>>6, slot = ((j>>3)&3)*16 + (b_lane>>1)*4 + (b_lane&1)*2
    //              + ((j>>5)&1), idx = j&7
    const int e0_tau  = j0 >> 6;
    const int e0_slot = ((j0 >> 3) & 3)*16 + (b_lane >> 1)*4 + (b_lane & 1)*2
                      + ((j0 >> 5) & 1);
    const int e0_idx  = j0 & 7;
    const int e1_tau  = j1 >> 6;
    const int e1_slot = ((j1 >> 3) & 3)*16 + (b_lane >> 1)*4 + (b_lane & 1)*2
                      + ((j1 >> 5) & 1);
    const int e1_idx  = j1 & 7;

    // ---- x stager (wave 15, lanes 0-31): depth-2 register pipeline ----
    // x[xi] at k = 224+xi -> tau 3, khalf=1, kq=(xi>>3):
    // slot = sq*16 + (sr8>>1)*4 + (sr8&1)*2 + 1
    const int srow = lane & 31, sq = srow >> 3, sr8 = srow & 7;
    const int sslot = sq*16 + (sr8 >> 1)*4 + (sr8 & 1)*2 + 1;
    const float* xrow_s = x + (size_t)(b0 + sr8) * IN_DIM + sq*8;
    const size_t tstride = (size_t)BATCH * IN_DIM;
    floatx4 sA0 = zero4, sA1 = zero4, sB0 = zero4, sB1 = zero4;

    auto issueLd = [&](int tn, floatx4& f0, floatx4& f1) {
        const float* p = xrow_s + (size_t)tn * tstride;
        f0 = *(const floatx4*)p;
        f1 = (sq < 3) ? *(const floatx4*)(p + 4) : zero4;   // IN=28 tail zeroed
    };
    auto commitX = [&](floatx4 f0, floatx4 f1, int buf) {
        half8 ax;
        ax[0] = (_Float16)f0[0]; ax[1] = (_Float16)f0[1];
        ax[2] = (_Float16)f0[2]; ax[3] = (_Float16)f0[3];
        ax[4] = (_Float16)f1[0]; ax[5] = (_Float16)f1[1];
        ax[6] = (_Float16)f1[2]; ax[7] = (_Float16)f1[3];
        *(half8*)&lds_A[buf][3][sslot][0] = ax;
    };

    __syncthreads();   // zero-fill visible before prologue writes

    if (wv == 15 && lane < 32) {
        floatx4 t0, t1;
        issueLd(0, t0, t1);           // x[0]
        issueLd(1, sA0, sA1);         // x[1] -> slot A
        issueLd(2, sB0, sB1);         // x[2] -> slot B
        commitX(t0, t1, 0);           // x[0] into buf 0 (read at step 0)
    }

    auto computeStep = [&](int rb, int wb, bool last) {
        if (!is_cw) return;
        floatx4 a0 = {bias0, bias0, bias0, bias0};
        floatx4 a1 = {bias1, bias1, bias1, bias1};
        #pragma unroll
        for (int tau = 0; tau < NTAU; ++tau) {
            const half8 av = *(const half8*)&lds_A[rb][tau][aslot][0];
            a0 = mfma16(av, Bf0[tau], a0);
            if (g1_on) a1 = mfma16(av, Bf1[tau], a1);
        }
        // ---- combine diagonal partials, DPP in full-EXEC straight line ----
        // Lane holds D[4q+r][n16]: r0=(b=2q,lo) r1=(b=2q,hi) r2=(b=2q+1,lo)
        // r3=(b=2q+1,hi). Lo-lane (n16<8) finishes b=2q, needs partner's r1;
        // hi-lane finishes b=2q+1, needs partner's r2. Pre-select what the
        // PARTNER needs, ONE row_ror:8 per group, then own-reg select + add.
        const float send0 = (n16 < 8) ? a0[2] : a0[1];
        const float send1 = (n16 < 8) ? a1[2] : a1[1];
        const float recv0 = ror8(send0);
        const float recv1 = ror8(send1);
        const float s0 = ((n16 < 8) ? a0[0] : a0[3]) + recv0;
        const float s1 = ((n16 < 8) ? a1[0] : a1[3]) + recv1;
        if (j0 < HID) {
            const float v = fast_tanh(s0);
            lds_A[wb][e0_tau][e0_slot][e0_idx] = (_Float16)v;
            if (last) lds_h[b_lane][j0] = v;
        }
        if (g1_on) {
            const float v = fast_tanh(s1);
            lds_A[wb][e1_tau][e1_slot][e1_idx] = (_Float16)v;
            if (last) lds_h[b_lane][j1] = v;
        }
    };

    // ================= time loop, 2 steps/iter (static reg slots) =========
    // even step t:  commit slot A (x[t+1]) -> buf1, refill A with x[t+3]
    // odd step t+1: commit slot B (x[t+2]) -> buf0, refill B with x[t+4]
    #pragma unroll 1
    for (int t = 0; t < T_STEPS; t += 2) {
        __syncthreads();
        if (wv == 15 && lane < 32) {
            commitX(sA0, sA1, 1);
            const int tn = (t+3 < T_STEPS) ? (t+3) : (T_STEPS-1);
            issueLd(tn, sA0, sA1);
        }
        computeStep(0, 1, false);

        __syncthreads();
        if (wv == 15 && lane < 32) {
            commitX(sB0, sB1, 0);
            const int tn = (t+4 < T_STEPS) ? (t+4) : (T_STEPS-1);
            issueLd(tn, sB0, sB1);
        }
        computeStep(1, 0, (t + 2) == T_STEPS);
    }

    __syncthreads();

    // ---- output: out[b][o] = sum_k h[b][k]*A[o][k] + c[o] (tiny, scalar) ----
    if (tid < BB * OUT_DIM) {
        const int r = tid / OUT_DIM;
        const int o = tid % OUT_DIM;
        float s = cvec[o];
        for (int k = 0; k < HID; ++k) s += lds_h[r][k] * A[o*HID + k];
        out[(size_t)(b0 + r) * OUT_DIM + o] = s;
    }
}

extern "C" void kernel_launch(void* const* d_in, const int* in_sizes, int n_in,
                              void* d_out, int out_size, void* d_ws, size_t ws_size,
                              hipStream_t stream) {
    const float* x  = (const float*)d_in[0];
    const float* H  = (const float*)d_in[1];
    const float* U  = (const float*)d_in[2];
    const float* A  = (const float*)d_in[3];
    const float* b  = (const float*)d_in[4];
    const float* c  = (const float*)d_in[5];
    float* out = (float*)d_out;

    rnn_kernel<<<dim3(BATCH / BB), dim3(NTHREADS), 0, stream>>>(x, H, U, A, b, c, out);
}